// Round 3
// baseline (22631.471 us; speedup 1.0000x reference)
//
#include <hip/hip_runtime.h>
#include <hip/hip_bf16.h>
#include <cstdint>
#include <cstddef>

#define N_NODES 2048
#define SEQ 512
#define HIDDEN 256
#define N_FEAT 9
#define N_EDGES 65536
#define N_LAYERS 3
#define STEP_AHEAD 14

#define GRU_BLOCKS 256   // 256 blocks * 4 waves * 2 j/wave = 2048 j's; 1 block/CU

// ---------- helpers ----------
__device__ __forceinline__ float bf2f(__hip_bfloat16 b) { return __bfloat162float(b); }
__device__ __forceinline__ float2 bfpair(unsigned v) {
  float2 f;
  f.x = __uint_as_float(v << 16);
  f.y = __uint_as_float(v & 0xffff0000u);
  return f;
}
// dtype-adaptive scalar float load: f32flag ? float : bf16
__device__ __forceinline__ float ldf(const void* p, size_t i, int f32flag) {
  return f32flag ? ((const float*)p)[i] : bf2f(((const __hip_bfloat16*)p)[i]);
}
// dtype-adaptive index load: i64flag ? int64 : int32
__device__ __forceinline__ int ldi(const void* p, size_t i, int i64flag) {
  return i64flag ? (int)((const long long*)p)[i] : ((const int*)p)[i];
}
struct F8 { float v[8]; };
// load 8 consecutive float-typed elements (16B bf16 or 32B f32), element index i
__device__ __forceinline__ F8 load8(const void* p, size_t i, int f32flag) {
  F8 r;
  if (f32flag) {
    const float4* q = (const float4*)((const float*)p + i);
    float4 a = q[0], b = q[1];
    r.v[0]=a.x; r.v[1]=a.y; r.v[2]=a.z; r.v[3]=a.w;
    r.v[4]=b.x; r.v[5]=b.y; r.v[6]=b.z; r.v[7]=b.w;
  } else {
    uint4 u = *(const uint4*)((const __hip_bfloat16*)p + i);
    float2 a = bfpair(u.x), b = bfpair(u.y), c = bfpair(u.z), d = bfpair(u.w);
    r.v[0]=a.x; r.v[1]=a.y; r.v[2]=b.x; r.v[3]=b.y;
    r.v[4]=c.x; r.v[5]=c.y; r.v[6]=d.x; r.v[7]=d.y;
  }
  return r;
}

// ---------- dtype detector: flags[0]=1 if floats are f32; flags[1]=1 if edge_index is int64 ----------
__global__ void k_detect(const void* __restrict__ x, const void* __restrict__ ei,
                         int* __restrict__ flags) {
  if (blockIdx.x == 0 && threadIdx.x == 0) {
    const unsigned short* hb = (const unsigned short*)x;
    int abn = 0;
    for (int i = 0; i < 4096; ++i) {
      unsigned short h = hb[i * 64];
      unsigned e = (h >> 7) & 0xFF;
      if (e > 140 || (e != 0 && e < 114)) abn++;
    }
    flags[0] = (abn > 256) ? 1 : 0;
    const int* ip = (const int*)ei;
    int nz = 0;
    for (int i = 0; i < 1024; ++i) nz += (ip[2 * i + 1] != 0);
    flags[1] = (nz == 0) ? 1 : 0;
  }
}

// ---------- 1x1 conv over channels ----------
__global__ __launch_bounds__(256) void k_conv(const void* __restrict__ x,
                                              const void* __restrict__ cw,
                                              const void* __restrict__ cb,
                                              const int* __restrict__ flags,
                                              float* __restrict__ out0) {
  const int F32 = flags[0];
  int i = blockIdx.x * 256 + threadIdx.x;
  float acc = ldf(cb, 0, F32);
#pragma unroll
  for (int f = 0; f < N_FEAT; ++f)
    acc += ldf(x, (size_t)f * (N_NODES * SEQ) + i, F32) * ldf(cw, f, F32);
  out0[i] = acc;
}

// ---------- h0 = out0(2048x512) @ gcn_w(512x256) ----------
__global__ __launch_bounds__(256) void k_gemm_h0(const float* __restrict__ out0,
                                                 const void* __restrict__ gw,
                                                 const int* __restrict__ flags,
                                                 float* __restrict__ h0) {
  const int F32 = flags[0];
  __shared__ float row[SEQ];
  int n = blockIdx.x, tid = threadIdx.x;
  row[tid] = out0[(size_t)n * SEQ + tid];
  row[tid + 256] = out0[(size_t)n * SEQ + 256 + tid];
  __syncthreads();
  float acc = 0.f;
#pragma unroll 4
  for (int s = 0; s < SEQ; ++s)
    acc = fmaf(row[s], ldf(gw, (size_t)s * HIDDEN + tid, F32), acc);
  h0[(size_t)n * HIDDEN + tid] = acc;
}

// ---------- degree + in-degree count ----------
__global__ __launch_bounds__(256) void k_deg(const void* __restrict__ ei,
                                             const void* __restrict__ ew,
                                             const int* __restrict__ flags,
                                             float* __restrict__ deg, int* __restrict__ cnt) {
  const int F32 = flags[0], I64 = flags[1];
  int e = blockIdx.x * 256 + threadIdx.x;
  if (e < N_EDGES) {
    int c = ldi(ei, (size_t)N_EDGES + e, I64);
    atomicAdd(&deg[c], ldf(ew, e, F32));
    atomicAdd(&cnt[c], 1);
  }
}

// ---------- dinv = rsqrt(deg + 1) ----------
__global__ __launch_bounds__(256) void k_dinv(const float* __restrict__ deg,
                                              float* __restrict__ dinv) {
  int n = blockIdx.x * 256 + threadIdx.x;
  dinv[n] = rsqrtf(deg[n] + 1.0f);
}

// ---------- exclusive scan of cnt[2048] -> offs ----------
__global__ __launch_bounds__(256) void k_scan(const int* __restrict__ cnt, int* __restrict__ offs) {
  __shared__ int s[N_NODES];
  __shared__ int csum[64];
  int tid = threadIdx.x;
  for (int k = tid; k < N_NODES; k += 256) s[k] = cnt[k];
  __syncthreads();
  if (tid < 64) {
    int a = 0;
    for (int k = 0; k < 32; ++k) a += s[tid * 32 + k];
    csum[tid] = a;
  }
  __syncthreads();
  if (tid == 0) {
    int run = 0;
    for (int i = 0; i < 64; ++i) { int v = csum[i]; csum[i] = run; run += v; }
  }
  __syncthreads();
  if (tid < 64) {
    int run = csum[tid];
    for (int k = 0; k < 32; ++k) {
      int n = tid * 32 + k;
      offs[n] = run;
      run += s[n];
    }
  }
}

// ---------- scatter edges into CSR grouped by target ----------
__global__ __launch_bounds__(256) void k_scatter(const void* __restrict__ ei,
                                                 const void* __restrict__ ew,
                                                 const int* __restrict__ flags,
                                                 const float* __restrict__ dinv,
                                                 const int* __restrict__ offs,
                                                 int* __restrict__ cursor,
                                                 int* __restrict__ csr_src,
                                                 float* __restrict__ csr_nrm) {
  const int F32 = flags[0], I64 = flags[1];
  int e = blockIdx.x * 256 + threadIdx.x;
  if (e < N_EDGES) {
    int r = ldi(ei, e, I64), c = ldi(ei, (size_t)N_EDGES + e, I64);
    float w = ldf(ew, e, F32);
    int pos = offs[c] + atomicAdd(&cursor[c], 1);
    csr_src[pos] = r;
    csr_nrm[pos] = dinv[r] * w * dinv[c];
  }
}

// ---------- aggregate + bias + relu, write transposed seq0[c*N + n] ----------
__global__ __launch_bounds__(256) void k_agg(const float* __restrict__ h0,
                                             const int* __restrict__ csr_src,
                                             const float* __restrict__ csr_nrm,
                                             const int* __restrict__ offs,
                                             const int* __restrict__ cnt,
                                             const float* __restrict__ dinv,
                                             const void* __restrict__ gb,
                                             const int* __restrict__ flags,
                                             float* __restrict__ seq0) {
  const int F32 = flags[0];
  int n = blockIdx.x, c = threadIdx.x;
  float acc = dinv[n] * dinv[n] * h0[(size_t)n * HIDDEN + c];
  int st = offs[n], en = st + cnt[n];
  for (int p = st; p < en; ++p)
    acc = fmaf(csr_nrm[p], h0[(size_t)csr_src[p] * HIDDEN + c], acc);
  float h = acc + ldf(gb, c, F32);
  seq0[(size_t)c * N_NODES + n] = h > 0.f ? h : 0.f;
}

// ---------- C(MxN) = A(MxK,f32) @ B(NxK)^T + bias(N); B/bias offset by layer in elements ----------
#define BM 32
#define BN 64
#define BK 32
__global__ __launch_bounds__(256) void k_gemm_nt(const float* __restrict__ A,
                                                 const void* __restrict__ B,
                                                 const void* __restrict__ bias,
                                                 const int* __restrict__ flags,
                                                 float* __restrict__ C,
                                                 int M, int N, int K,
                                                 size_t b_off, size_t bias_off) {
  const int F32 = flags[0];
  __shared__ float As[BM][BK + 1];
  __shared__ float Bs[BN][BK + 1];
  int tid = threadIdx.x;
  int bm = blockIdx.x * BM, bn = blockIdx.y * BN;
  int tx = tid & 15, ty = tid >> 4;
  float acc[2][4] = {};
  for (int k0 = 0; k0 < K; k0 += BK) {
    {
      int row = tid >> 3, kc = (tid & 7) << 2;   // 32 rows x 8 float4
      float4 v = *(const float4*)(A + (size_t)(bm + row) * K + k0 + kc);
      As[row][kc] = v.x; As[row][kc + 1] = v.y; As[row][kc + 2] = v.z; As[row][kc + 3] = v.w;
    }
    {
      int row = tid >> 2, kc = (tid & 3) << 3;
      F8 b8 = load8(B, b_off + (size_t)(bn + row) * K + k0 + kc, F32);
#pragma unroll
      for (int u = 0; u < 8; ++u) Bs[row][kc + u] = b8.v[u];
    }
    __syncthreads();
#pragma unroll
    for (int kk = 0; kk < BK; ++kk) {
      float a[2], b[4];
#pragma unroll
      for (int i = 0; i < 2; ++i) a[i] = As[ty * 2 + i][kk];
#pragma unroll
      for (int j = 0; j < 4; ++j) b[j] = Bs[tx * 4 + j][kk];
#pragma unroll
      for (int i = 0; i < 2; ++i)
#pragma unroll
        for (int j = 0; j < 4; ++j) acc[i][j] = fmaf(a[i], b[j], acc[i][j]);
    }
    __syncthreads();
  }
#pragma unroll
  for (int i = 0; i < 2; ++i)
#pragma unroll
    for (int j = 0; j < 4; ++j) {
      int m = bm + ty * 2 + i, n = bn + tx * 4 + j;
      C[(size_t)m * N + n] = acc[i][j] + ldf(bias, bias_off + n, F32);
    }
}

// ---------- manual grid barrier (256 flags, one per block; monotone generations) ----------
// Release: __syncthreads drains this block's stores; thread-0 __threadfence writes L2
// back to the coherence point; agent-scope atomic store publishes. Acquire: post-spin
// __threadfence invalidates stale cache before reading remote h. Generations only
// increase and stores are absolute -> safe under rocprof dispatch replay.
__device__ __forceinline__ void grid_bar(int* gbar, int g) {
  __syncthreads();
  if (threadIdx.x == 0) {
    __threadfence();
    __hip_atomic_store(&gbar[blockIdx.x], g, __ATOMIC_RELAXED, __HIP_MEMORY_SCOPE_AGENT);
  }
  int spins = 0;
  while (__hip_atomic_load(&gbar[threadIdx.x], __ATOMIC_RELAXED, __HIP_MEMORY_SCOPE_AGENT) < g) {
    __builtin_amdgcn_s_sleep(2);
    if (++spins > (1 << 14)) break;  // bounded: fails visibly (wrong result), never watchdog
  }
  __threadfence();
  __syncthreads();
}

// ---------- persistent GRU layer (cooperative launch): all 256 steps in one kernel ----------
// 256 blocks x 256 threads, 1 block/CU (weakest residency req). Each wave owns 2 hidden
// indices; its whh slice (2 j x 3 gates x 2048) is register-staged once per layer
// (bf16: 96 VGPR, f32: 192 VGPR; launch_bounds(256,1) -> 512 VGPR budget, no spill).
__global__ __launch_bounds__(256, 1) void k_gru_persist(
    const float* __restrict__ gi, const void* __restrict__ whh,
    const void* __restrict__ bhh, const int* __restrict__ flags,
    const float* __restrict__ hinit, float* __restrict__ sout,
    float* __restrict__ ysT, int* __restrict__ gbar,
    size_t w_off, size_t b_off, int gen0) {
  const int F32 = flags[0];
  const int tid = threadIdx.x;
  const int wv = tid >> 6, lane = tid & 63;
  const int jbase = (blockIdx.x << 3) + (wv << 1);   // this wave's 2 j's

  float bh[2][3];
#pragma unroll
  for (int jj = 0; jj < 2; ++jj)
#pragma unroll
    for (int g = 0; g < 3; ++g) bh[jj][g] = 0.f;
  if (lane == 0) {
#pragma unroll
    for (int jj = 0; jj < 2; ++jj)
#pragma unroll
      for (int g = 0; g < 3; ++g)
        bh[jj][g] = ldf(bhh, b_off + (size_t)g * 2048 + jbase + jj, F32);
  }

  if (!F32) {
    // ---- bf16: stage 2 j x 3 gates x 32 k into 24 uint4 (96 VGPR) ----
    const __hip_bfloat16* wb = (const __hip_bfloat16*)whh + w_off;
    uint4 W[2][3][4];
#pragma unroll
    for (int jj = 0; jj < 2; ++jj)
#pragma unroll
      for (int g = 0; g < 3; ++g) {
        const __hip_bfloat16* r = wb + (size_t)(jbase + jj + g * 2048) * 2048;
#pragma unroll
        for (int i = 0; i < 4; ++i)
          W[jj][g][i] = *(const uint4*)(r + ((lane + (i << 6)) << 3));
      }
    for (int t = 0; t < HIDDEN; ++t) {
      const float* hsrc = t ? (sout + (size_t)(t - 1) * N_NODES) : hinit;
      float s[2][3] = {};
#pragma unroll
      for (int i = 0; i < 4; ++i) {
        const float4* hp = (const float4*)(hsrc + ((lane + (i << 6)) << 3));
        float4 va = hp[0], vb = hp[1];
        float hv[8] = {va.x, va.y, va.z, va.w, vb.x, vb.y, vb.z, vb.w};
#pragma unroll
        for (int jj = 0; jj < 2; ++jj)
#pragma unroll
          for (int g = 0; g < 3; ++g) {
            uint4 w = W[jj][g][i];
            float2 p0 = bfpair(w.x), p1 = bfpair(w.y), p2 = bfpair(w.z), p3 = bfpair(w.w);
            float acc = s[jj][g];
            acc = fmaf(hv[0], p0.x, acc); acc = fmaf(hv[1], p0.y, acc);
            acc = fmaf(hv[2], p1.x, acc); acc = fmaf(hv[3], p1.y, acc);
            acc = fmaf(hv[4], p2.x, acc); acc = fmaf(hv[5], p2.y, acc);
            acc = fmaf(hv[6], p3.x, acc); acc = fmaf(hv[7], p3.y, acc);
            s[jj][g] = acc;
          }
      }
#pragma unroll
      for (int off = 32; off; off >>= 1)
#pragma unroll
        for (int jj = 0; jj < 2; ++jj)
#pragma unroll
          for (int g = 0; g < 3; ++g) s[jj][g] += __shfl_down(s[jj][g], off);
      if (lane == 0) {
        const size_t g0 = (size_t)t * (3 * N_NODES);
#pragma unroll
        for (int jj = 0; jj < 2; ++jj) {
          int j = jbase + jj;
          float gir = gi[g0 + j], giz = gi[g0 + 2048 + j], gin = gi[g0 + 4096 + j];
          float r = 1.f / (1.f + expf(-(gir + s[jj][0] + bh[jj][0])));
          float z = 1.f / (1.f + expf(-(giz + s[jj][1] + bh[jj][1])));
          float nn = tanhf(gin + r * (s[jj][2] + bh[jj][2]));
          float hn = (1.f - z) * nn + z * hsrc[j];
          sout[(size_t)t * N_NODES + j] = hn;
          if (ysT) ysT[((size_t)j << 8) + t] = hn;
        }
      }
      grid_bar(gbar, gen0 + t + 1);
    }
  } else {
    // ---- f32: stage 2 j x 3 gates x 32 k into 48 float4 (192 VGPR) ----
    const float* wf = (const float*)whh + w_off;
    float4 W[2][3][8];
#pragma unroll
    for (int jj = 0; jj < 2; ++jj)
#pragma unroll
      for (int g = 0; g < 3; ++g) {
        const float* r = wf + (size_t)(jbase + jj + g * 2048) * 2048;
#pragma unroll
        for (int i = 0; i < 4; ++i) {
          const float4* q = (const float4*)(r + ((lane + (i << 6)) << 3));
          W[jj][g][2 * i] = q[0];
          W[jj][g][2 * i + 1] = q[1];
        }
      }
    for (int t = 0; t < HIDDEN; ++t) {
      const float* hsrc = t ? (sout + (size_t)(t - 1) * N_NODES) : hinit;
      float s[2][3] = {};
#pragma unroll
      for (int i = 0; i < 4; ++i) {
        const float4* hp = (const float4*)(hsrc + ((lane + (i << 6)) << 3));
        float4 va = hp[0], vb = hp[1];
#pragma unroll
        for (int jj = 0; jj < 2; ++jj)
#pragma unroll
          for (int g = 0; g < 3; ++g) {
            float4 xa = W[jj][g][2 * i], xb = W[jj][g][2 * i + 1];
            float acc = s[jj][g];
            acc = fmaf(va.x, xa.x, acc); acc = fmaf(va.y, xa.y, acc);
            acc = fmaf(va.z, xa.z, acc); acc = fmaf(va.w, xa.w, acc);
            acc = fmaf(vb.x, xb.x, acc); acc = fmaf(vb.y, xb.y, acc);
            acc = fmaf(vb.z, xb.z, acc); acc = fmaf(vb.w, xb.w, acc);
            s[jj][g] = acc;
          }
      }
#pragma unroll
      for (int off = 32; off; off >>= 1)
#pragma unroll
        for (int jj = 0; jj < 2; ++jj)
#pragma unroll
          for (int g = 0; g < 3; ++g) s[jj][g] += __shfl_down(s[jj][g], off);
      if (lane == 0) {
        const size_t g0 = (size_t)t * (3 * N_NODES);
#pragma unroll
        for (int jj = 0; jj < 2; ++jj) {
          int j = jbase + jj;
          float gir = gi[g0 + j], giz = gi[g0 + 2048 + j], gin = gi[g0 + 4096 + j];
          float r = 1.f / (1.f + expf(-(gir + s[jj][0] + bh[jj][0])));
          float z = 1.f / (1.f + expf(-(giz + s[jj][1] + bh[jj][1])));
          float nn = tanhf(gin + r * (s[jj][2] + bh[jj][2]));
          float hn = (1.f - z) * nn + z * hsrc[j];
          sout[(size_t)t * N_NODES + j] = hn;
          if (ysT) ysT[((size_t)j << 8) + t] = hn;
        }
      }
      grid_bar(gbar, gen0 + t + 1);
    }
  }
}

// ---------- one GRU time step (fallback path if cooperative launch is refused) ----------
__global__ __launch_bounds__(256) void k_gru_step(const float* __restrict__ gi,
                                                  const void* __restrict__ whh,
                                                  const void* __restrict__ bhh,
                                                  const int* __restrict__ flags,
                                                  const float* __restrict__ hprev,
                                                  float* __restrict__ ysrow,
                                                  float* __restrict__ ysT,
                                                  int t, size_t w_off, size_t b_off) {
  const int F32 = flags[0];
  int j = blockIdx.x, tid = threadIdx.x;
  int k0 = tid << 3;
  const float4* hp4 = (const float4*)(hprev + k0);
  float4 hA = hp4[0], hB = hp4[1];
  F8 w0 = load8(whh, w_off + ((size_t)j << 11) + k0, F32);
  F8 w1 = load8(whh, w_off + ((size_t)(j + 2048) << 11) + k0, F32);
  F8 w2 = load8(whh, w_off + ((size_t)(j + 4096) << 11) + k0, F32);
  float hv[8] = {hA.x, hA.y, hA.z, hA.w, hB.x, hB.y, hB.z, hB.w};
  float s0 = 0.f, s1 = 0.f, s2 = 0.f;
#pragma unroll
  for (int u = 0; u < 8; ++u) {
    s0 = fmaf(hv[u], w0.v[u], s0);
    s1 = fmaf(hv[u], w1.v[u], s1);
    s2 = fmaf(hv[u], w2.v[u], s2);
  }
#pragma unroll
  for (int off = 32; off; off >>= 1) {
    s0 += __shfl_down(s0, off);
    s1 += __shfl_down(s1, off);
    s2 += __shfl_down(s2, off);
  }
  __shared__ float red[12];
  int wid = tid >> 6, lane = tid & 63;
  if (lane == 0) { red[wid] = s0; red[4 + wid] = s1; red[8 + wid] = s2; }
  __syncthreads();
  if (tid == 0) {
    float d0 = red[0] + red[1] + red[2] + red[3];
    float d1 = red[4] + red[5] + red[6] + red[7];
    float d2 = red[8] + red[9] + red[10] + red[11];
    const size_t g = (size_t)t * (3 * N_NODES);
    float gir = gi[g + j], giz = gi[g + 2048 + j], gin = gi[g + 4096 + j];
    float ghr = d0 + ldf(bhh, b_off + j, F32);
    float ghz = d1 + ldf(bhh, b_off + 2048 + j, F32);
    float ghn = d2 + ldf(bhh, b_off + 4096 + j, F32);
    float r = 1.f / (1.f + expf(-(gir + ghr)));
    float z = 1.f / (1.f + expf(-(giz + ghz)));
    float nn = tanhf(gin + r * ghn);
    float hn = (1.f - z) * nn + z * hprev[j];
    ysrow[j] = hn;
    if (ysT) ysT[(size_t)j * HIDDEN + t] = hn;
  }
}

// ---------- final linear ----------
__global__ __launch_bounds__(256) void k_final(const float* __restrict__ ysT,
                                               const void* __restrict__ lw,
                                               const void* __restrict__ lb,
                                               const int* __restrict__ flags,
                                               void* __restrict__ outp) {
  const int F32 = flags[0];
  __shared__ float row[HIDDEN];
  int n = blockIdx.x, tid = threadIdx.x;
  row[tid] = ysT[(size_t)n * HIDDEN + tid];
  __syncthreads();
  if (tid < STEP_AHEAD) {
    float acc = ldf(lb, tid, F32);
    for (int t = 0; t < HIDDEN; ++t)
      acc = fmaf(row[t], ldf(lw, (size_t)t * STEP_AHEAD + tid, F32), acc);
    if (F32) ((float*)outp)[(size_t)n * STEP_AHEAD + tid] = acc;
    else ((__hip_bfloat16*)outp)[(size_t)n * STEP_AHEAD + tid] = __float2bfloat16(acc);
  }
}

extern "C" void kernel_launch(void* const* d_in, const int* in_sizes, int n_in,
                              void* d_out, int out_size, void* d_ws, size_t ws_size,
                              hipStream_t stream) {
  const void* x   = d_in[0];
  const void* ei  = d_in[1];
  const void* ew  = d_in[2];
  const void* cw  = d_in[3];
  const void* cb  = d_in[4];
  const void* gw  = d_in[5];
  const void* gb  = d_in[6];
  const void* wih = d_in[7];
  const void* whh = d_in[8];
  const void* bih = d_in[9];
  const void* bhh = d_in[10];
  const void* lw  = d_in[11];
  const void* lb  = d_in[12];

  // workspace layout (floats), lifetime-aliased (~13.2 MB)
  float* ws = (float*)d_ws;
  float* gi   = ws;                                // 1,572,864 f (6 MB)
  float* out0 = ws;                                // aliases gi[0:1M) - dead before gi written
  float* seqA = ws + 1572864;                      // 524,288 f
  float* seqB = seqA + 524288;                     // 524,288 f
  float* h0   = seqB + 524288;                     // 524,288 f (dead after k_agg)
  float* ysT  = h0;                                // aliases h0 - written only in layer 2
  float* zreg = h0 + 524288;                       // 8,192 f zeroed: deg,cnt,cur,hinit
  float* deg   = zreg;
  int*   cnt   = (int*)(zreg + N_NODES);
  int*   cur   = (int*)(zreg + 2 * N_NODES);
  float* hinit = zreg + 3 * N_NODES;
  float* dinv = zreg + 4 * N_NODES;                // 2,048 f
  int*   csr_src = (int*)(dinv + N_NODES);         // 65,536
  float* csr_nrm = (float*)(csr_src + N_EDGES);    // 65,536
  int*   offs = (int*)(csr_nrm + N_EDGES);         // 2,048
  int*   flags = offs + N_NODES;                   // 2
  int*   gbar = cur;                               // reuse cursor region (dead after k_scatter)

  k_detect<<<1, 64, 0, stream>>>(x, ei, flags);
  (void)hipMemsetAsync(zreg, 0, 4 * N_NODES * sizeof(float), stream);

  k_conv<<<(N_NODES * SEQ) / 256, 256, 0, stream>>>(x, cw, cb, flags, out0);
  k_gemm_h0<<<N_NODES, 256, 0, stream>>>(out0, gw, flags, h0);
  k_deg<<<N_EDGES / 256, 256, 0, stream>>>(ei, ew, flags, deg, cnt);
  k_dinv<<<N_NODES / 256, 256, 0, stream>>>(deg, dinv);
  k_scan<<<1, 256, 0, stream>>>(cnt, offs);
  k_scatter<<<N_EDGES / 256, 256, 0, stream>>>(ei, ew, flags, dinv, offs, cur, csr_src, csr_nrm);
  k_agg<<<N_NODES, 256, 0, stream>>>(h0, csr_src, csr_nrm, offs, cnt, dinv, gb, flags, seqA);

  // zero barrier flags (cursor region is dead after k_scatter)
  (void)hipMemsetAsync(gbar, 0, GRU_BLOCKS * sizeof(int), stream);

  const size_t WL = (size_t)3 * N_NODES * N_NODES;  // per-layer weight stride (elements)
  const size_t BL = (size_t)3 * N_NODES;            // per-layer bias stride (elements)
  for (int l = 0; l < N_LAYERS; ++l) {
    float* sin  = (l & 1) ? seqB : seqA;
    float* sout = (l & 1) ? seqA : seqB;
    k_gemm_nt<<<dim3(HIDDEN / BM, (3 * N_NODES) / BN), 256, 0, stream>>>(
        sin, wih, bih, flags, gi, HIDDEN, 3 * N_NODES, N_NODES,
        (size_t)l * WL, (size_t)l * BL);
    float* ysTp = (l == N_LAYERS - 1) ? ysT : (float*)nullptr;

    // cooperative launch: validates co-residency at launch; falls back if refused
    const float* a_gi = gi;   const void* a_whh = whh; const void* a_bhh = bhh;
    const int* a_flags = flags; const float* a_hinit = hinit;
    float* a_sout = sout;     float* a_ysT = ysTp;     int* a_gbar = gbar;
    size_t a_wo = (size_t)l * WL, a_bo = (size_t)l * BL;
    int a_g0 = l * HIDDEN;
    void* args[] = {&a_gi, &a_whh, &a_bhh, &a_flags, &a_hinit,
                    &a_sout, &a_ysT, &a_gbar, &a_wo, &a_bo, &a_g0};
    hipError_t rc = hipLaunchCooperativeKernel(
        reinterpret_cast<void*>(k_gru_persist),
        dim3(GRU_BLOCKS), dim3(256), args, 0, stream);
    if (rc != hipSuccess) {
      for (int t = 0; t < HIDDEN; ++t) {
        const float* hp = (t == 0) ? hinit : (sout + (size_t)(t - 1) * N_NODES);
        k_gru_step<<<N_NODES, 256, 0, stream>>>(
            gi, whh, bhh, flags, hp,
            sout + (size_t)t * N_NODES, ysTp, t, (size_t)l * WL, (size_t)l * BL);
      }
    }
  }
  k_final<<<N_NODES, 256, 0, stream>>>(ysT, lw, lb, flags, d_out);
}

// Round 4
// 11435.340 us; speedup vs baseline: 1.9791x; 1.9791x over previous
//
#include <hip/hip_runtime.h>
#include <hip/hip_bf16.h>
#include <cstdint>
#include <cstddef>

#define N_NODES 2048
#define SEQ 512
#define HIDDEN 256
#define N_FEAT 9
#define N_EDGES 65536
#define N_LAYERS 3
#define STEP_AHEAD 14

#define GRU_BLOCKS 256   // 256 blocks * 4 waves * 2 j/wave = 2048 j's; 1 block/CU

// ---------- helpers ----------
__device__ __forceinline__ float bf2f(__hip_bfloat16 b) { return __bfloat162float(b); }
__device__ __forceinline__ float2 bfpair(unsigned v) {
  float2 f;
  f.x = __uint_as_float(v << 16);
  f.y = __uint_as_float(v & 0xffff0000u);
  return f;
}
// dtype-adaptive scalar float load: f32flag ? float : bf16
__device__ __forceinline__ float ldf(const void* p, size_t i, int f32flag) {
  return f32flag ? ((const float*)p)[i] : bf2f(((const __hip_bfloat16*)p)[i]);
}
// dtype-adaptive index load: i64flag ? int64 : int32
__device__ __forceinline__ int ldi(const void* p, size_t i, int i64flag) {
  return i64flag ? (int)((const long long*)p)[i] : ((const int*)p)[i];
}
struct F8 { float v[8]; };
// load 8 consecutive float-typed elements (16B bf16 or 32B f32), element index i
__device__ __forceinline__ F8 load8(const void* p, size_t i, int f32flag) {
  F8 r;
  if (f32flag) {
    const float4* q = (const float4*)((const float*)p + i);
    float4 a = q[0], b = q[1];
    r.v[0]=a.x; r.v[1]=a.y; r.v[2]=a.z; r.v[3]=a.w;
    r.v[4]=b.x; r.v[5]=b.y; r.v[6]=b.z; r.v[7]=b.w;
  } else {
    uint4 u = *(const uint4*)((const __hip_bfloat16*)p + i);
    float2 a = bfpair(u.x), b = bfpair(u.y), c = bfpair(u.z), d = bfpair(u.w);
    r.v[0]=a.x; r.v[1]=a.y; r.v[2]=b.x; r.v[3]=b.y;
    r.v[4]=c.x; r.v[5]=c.y; r.v[6]=d.x; r.v[7]=d.y;
  }
  return r;
}

// ---------- dtype detector: flags[0]=1 if floats are f32; flags[1]=1 if edge_index is int64 ----------
__global__ void k_detect(const void* __restrict__ x, const void* __restrict__ ei,
                         int* __restrict__ flags) {
  if (blockIdx.x == 0 && threadIdx.x == 0) {
    const unsigned short* hb = (const unsigned short*)x;
    int abn = 0;
    for (int i = 0; i < 4096; ++i) {
      unsigned short h = hb[i * 64];
      unsigned e = (h >> 7) & 0xFF;
      if (e > 140 || (e != 0 && e < 114)) abn++;
    }
    flags[0] = (abn > 256) ? 1 : 0;
    const int* ip = (const int*)ei;
    int nz = 0;
    for (int i = 0; i < 1024; ++i) nz += (ip[2 * i + 1] != 0);
    flags[1] = (nz == 0) ? 1 : 0;
  }
}

// ---------- 1x1 conv over channels ----------
__global__ __launch_bounds__(256) void k_conv(const void* __restrict__ x,
                                              const void* __restrict__ cw,
                                              const void* __restrict__ cb,
                                              const int* __restrict__ flags,
                                              float* __restrict__ out0) {
  const int F32 = flags[0];
  int i = blockIdx.x * 256 + threadIdx.x;
  float acc = ldf(cb, 0, F32);
#pragma unroll
  for (int f = 0; f < N_FEAT; ++f)
    acc += ldf(x, (size_t)f * (N_NODES * SEQ) + i, F32) * ldf(cw, f, F32);
  out0[i] = acc;
}

// ---------- h0 = out0(2048x512) @ gcn_w(512x256) ----------
__global__ __launch_bounds__(256) void k_gemm_h0(const float* __restrict__ out0,
                                                 const void* __restrict__ gw,
                                                 const int* __restrict__ flags,
                                                 float* __restrict__ h0) {
  const int F32 = flags[0];
  __shared__ float row[SEQ];
  int n = blockIdx.x, tid = threadIdx.x;
  row[tid] = out0[(size_t)n * SEQ + tid];
  row[tid + 256] = out0[(size_t)n * SEQ + 256 + tid];
  __syncthreads();
  float acc = 0.f;
#pragma unroll 4
  for (int s = 0; s < SEQ; ++s)
    acc = fmaf(row[s], ldf(gw, (size_t)s * HIDDEN + tid, F32), acc);
  h0[(size_t)n * HIDDEN + tid] = acc;
}

// ---------- degree + in-degree count ----------
__global__ __launch_bounds__(256) void k_deg(const void* __restrict__ ei,
                                             const void* __restrict__ ew,
                                             const int* __restrict__ flags,
                                             float* __restrict__ deg, int* __restrict__ cnt) {
  const int F32 = flags[0], I64 = flags[1];
  int e = blockIdx.x * 256 + threadIdx.x;
  if (e < N_EDGES) {
    int c = ldi(ei, (size_t)N_EDGES + e, I64);
    atomicAdd(&deg[c], ldf(ew, e, F32));
    atomicAdd(&cnt[c], 1);
  }
}

// ---------- dinv = rsqrt(deg + 1) ----------
__global__ __launch_bounds__(256) void k_dinv(const float* __restrict__ deg,
                                              float* __restrict__ dinv) {
  int n = blockIdx.x * 256 + threadIdx.x;
  dinv[n] = rsqrtf(deg[n] + 1.0f);
}

// ---------- exclusive scan of cnt[2048] -> offs ----------
__global__ __launch_bounds__(256) void k_scan(const int* __restrict__ cnt, int* __restrict__ offs) {
  __shared__ int s[N_NODES];
  __shared__ int csum[64];
  int tid = threadIdx.x;
  for (int k = tid; k < N_NODES; k += 256) s[k] = cnt[k];
  __syncthreads();
  if (tid < 64) {
    int a = 0;
    for (int k = 0; k < 32; ++k) a += s[tid * 32 + k];
    csum[tid] = a;
  }
  __syncthreads();
  if (tid == 0) {
    int run = 0;
    for (int i = 0; i < 64; ++i) { int v = csum[i]; csum[i] = run; run += v; }
  }
  __syncthreads();
  if (tid < 64) {
    int run = csum[tid];
    for (int k = 0; k < 32; ++k) {
      int n = tid * 32 + k;
      offs[n] = run;
      run += s[n];
    }
  }
}

// ---------- scatter edges into CSR grouped by target ----------
__global__ __launch_bounds__(256) void k_scatter(const void* __restrict__ ei,
                                                 const void* __restrict__ ew,
                                                 const int* __restrict__ flags,
                                                 const float* __restrict__ dinv,
                                                 const int* __restrict__ offs,
                                                 int* __restrict__ cursor,
                                                 int* __restrict__ csr_src,
                                                 float* __restrict__ csr_nrm) {
  const int F32 = flags[0], I64 = flags[1];
  int e = blockIdx.x * 256 + threadIdx.x;
  if (e < N_EDGES) {
    int r = ldi(ei, e, I64), c = ldi(ei, (size_t)N_EDGES + e, I64);
    float w = ldf(ew, e, F32);
    int pos = offs[c] + atomicAdd(&cursor[c], 1);
    csr_src[pos] = r;
    csr_nrm[pos] = dinv[r] * w * dinv[c];
  }
}

// ---------- aggregate + bias + relu, write transposed seq0[c*N + n] ----------
__global__ __launch_bounds__(256) void k_agg(const float* __restrict__ h0,
                                             const int* __restrict__ csr_src,
                                             const float* __restrict__ csr_nrm,
                                             const int* __restrict__ offs,
                                             const int* __restrict__ cnt,
                                             const float* __restrict__ dinv,
                                             const void* __restrict__ gb,
                                             const int* __restrict__ flags,
                                             float* __restrict__ seq0) {
  const int F32 = flags[0];
  int n = blockIdx.x, c = threadIdx.x;
  float acc = dinv[n] * dinv[n] * h0[(size_t)n * HIDDEN + c];
  int st = offs[n], en = st + cnt[n];
  for (int p = st; p < en; ++p)
    acc = fmaf(csr_nrm[p], h0[(size_t)csr_src[p] * HIDDEN + c], acc);
  float h = acc + ldf(gb, c, F32);
  seq0[(size_t)c * N_NODES + n] = h > 0.f ? h : 0.f;
}

// ---------- C(MxN) = A(MxK,f32) @ B(NxK)^T + bias(N); B/bias offset by layer in elements ----------
#define BM 32
#define BN 64
#define BK 32
__global__ __launch_bounds__(256) void k_gemm_nt(const float* __restrict__ A,
                                                 const void* __restrict__ B,
                                                 const void* __restrict__ bias,
                                                 const int* __restrict__ flags,
                                                 float* __restrict__ C,
                                                 int M, int N, int K,
                                                 size_t b_off, size_t bias_off) {
  const int F32 = flags[0];
  __shared__ float As[BM][BK + 1];
  __shared__ float Bs[BN][BK + 1];
  int tid = threadIdx.x;
  int bm = blockIdx.x * BM, bn = blockIdx.y * BN;
  int tx = tid & 15, ty = tid >> 4;
  float acc[2][4] = {};
  for (int k0 = 0; k0 < K; k0 += BK) {
    {
      int row = tid >> 3, kc = (tid & 7) << 2;   // 32 rows x 8 float4
      float4 v = *(const float4*)(A + (size_t)(bm + row) * K + k0 + kc);
      As[row][kc] = v.x; As[row][kc + 1] = v.y; As[row][kc + 2] = v.z; As[row][kc + 3] = v.w;
    }
    {
      int row = tid >> 2, kc = (tid & 3) << 3;
      F8 b8 = load8(B, b_off + (size_t)(bn + row) * K + k0 + kc, F32);
#pragma unroll
      for (int u = 0; u < 8; ++u) Bs[row][kc + u] = b8.v[u];
    }
    __syncthreads();
#pragma unroll
    for (int kk = 0; kk < BK; ++kk) {
      float a[2], b[4];
#pragma unroll
      for (int i = 0; i < 2; ++i) a[i] = As[ty * 2 + i][kk];
#pragma unroll
      for (int j = 0; j < 4; ++j) b[j] = Bs[tx * 4 + j][kk];
#pragma unroll
      for (int i = 0; i < 2; ++i)
#pragma unroll
        for (int j = 0; j < 4; ++j) acc[i][j] = fmaf(a[i], b[j], acc[i][j]);
    }
    __syncthreads();
  }
#pragma unroll
  for (int i = 0; i < 2; ++i)
#pragma unroll
    for (int j = 0; j < 4; ++j) {
      int m = bm + ty * 2 + i, n = bn + tx * 4 + j;
      C[(size_t)m * N + n] = acc[i][j] + ldf(bias, bias_off + n, F32);
    }
}

// ---------- grid barrier v2: tree arrive + single gen word, 1 poller/block ----------
// Counters are CUMULATIVE (monotone) -> no reset, replay-safe. Layout in c[]:
// c[0..7] group counters (32 blocks each), c[8] root, c[9] generation.
// h was published with agent-scope atomic stores (write-through to coherence point),
// drained by the vmcnt(0) that __syncthreads emits -> no release fence needed.
// Freshness: one ACQUIRE load after the relaxed poll (emits L1/L2 invalidate);
// thread 0's cache-wide inv covers the whole CU (1 block/CU).
__device__ __forceinline__ void grid_bar(int* c, int g) {
  __syncthreads();
  if (threadIdx.x == 0) {
    int grp = blockIdx.x >> 5;
    int old = __hip_atomic_fetch_add(&c[grp], 1, __ATOMIC_RELAXED, __HIP_MEMORY_SCOPE_AGENT);
    if (old == 32 * g - 1) {
      int r = __hip_atomic_fetch_add(&c[8], 1, __ATOMIC_RELAXED, __HIP_MEMORY_SCOPE_AGENT);
      if (r == 8 * g - 1)
        __hip_atomic_store(&c[9], g, __ATOMIC_RELAXED, __HIP_MEMORY_SCOPE_AGENT);
    }
    int spins = 0;
    while (__hip_atomic_load(&c[9], __ATOMIC_RELAXED, __HIP_MEMORY_SCOPE_AGENT) < g) {
      __builtin_amdgcn_s_sleep(4);
      if (++spins > (1 << 14)) break;  // bounded: fails visibly, never hangs
    }
    (void)__hip_atomic_load(&c[9], __ATOMIC_ACQUIRE, __HIP_MEMORY_SCOPE_AGENT);  // inv L1/L2
  }
  __syncthreads();
}

// publish one h value to the coherence point (write-through, vmcnt-tracked)
__device__ __forceinline__ void pub(float* p, float v) {
  __hip_atomic_store(p, v, __ATOMIC_RELAXED, __HIP_MEMORY_SCOPE_AGENT);
}

// ---------- persistent GRU layer (cooperative launch): all 256 steps in one kernel ----------
// 256 blocks x 256 threads, 1 block/CU. Each wave owns 2 hidden indices; its whh slice
// is register-staged once per layer (bf16: 96 VGPR, f32: 192 VGPR).
__global__ __launch_bounds__(256, 1) void k_gru_persist(
    const float* __restrict__ gi, const void* __restrict__ whh,
    const void* __restrict__ bhh, const int* __restrict__ flags,
    const float* __restrict__ hinit, float* __restrict__ sout,
    float* __restrict__ ysT, int* __restrict__ gbar,
    size_t w_off, size_t b_off, int gen0) {
  const int F32 = flags[0];
  const int tid = threadIdx.x;
  const int wv = tid >> 6, lane = tid & 63;
  const int jbase = (blockIdx.x << 3) + (wv << 1);   // this wave's 2 j's

  float bh[2][3];
#pragma unroll
  for (int jj = 0; jj < 2; ++jj)
#pragma unroll
    for (int g = 0; g < 3; ++g) bh[jj][g] = 0.f;
  float pr[2], pz[2], pn[2];   // prefetched gi gates for current t
  if (lane == 0) {
#pragma unroll
    for (int jj = 0; jj < 2; ++jj) {
#pragma unroll
      for (int g = 0; g < 3; ++g)
        bh[jj][g] = ldf(bhh, b_off + (size_t)g * 2048 + jbase + jj, F32);
      pr[jj] = gi[jbase + jj];
      pz[jj] = gi[2048 + jbase + jj];
      pn[jj] = gi[4096 + jbase + jj];
    }
  }

  if (!F32) {
    // ---- bf16: stage 2 j x 3 gates x 32 k into 24 uint4 (96 VGPR) ----
    const __hip_bfloat16* wb = (const __hip_bfloat16*)whh + w_off;
    uint4 W[2][3][4];
#pragma unroll
    for (int jj = 0; jj < 2; ++jj)
#pragma unroll
      for (int g = 0; g < 3; ++g) {
        const __hip_bfloat16* r = wb + (size_t)(jbase + jj + g * 2048) * 2048;
#pragma unroll
        for (int i = 0; i < 4; ++i)
          W[jj][g][i] = *(const uint4*)(r + ((lane + (i << 6)) << 3));
      }
    for (int t = 0; t < HIDDEN; ++t) {
      const float* hsrc = t ? (sout + (size_t)(t - 1) * N_NODES) : hinit;
      float s[2][3] = {};
#pragma unroll
      for (int i = 0; i < 4; ++i) {
        const float4* hp = (const float4*)(hsrc + ((lane + (i << 6)) << 3));
        float4 va = hp[0], vb = hp[1];
        float hv[8] = {va.x, va.y, va.z, va.w, vb.x, vb.y, vb.z, vb.w};
#pragma unroll
        for (int jj = 0; jj < 2; ++jj)
#pragma unroll
          for (int g = 0; g < 3; ++g) {
            uint4 w = W[jj][g][i];
            float2 p0 = bfpair(w.x), p1 = bfpair(w.y), p2 = bfpair(w.z), p3 = bfpair(w.w);
            float acc = s[jj][g];
            acc = fmaf(hv[0], p0.x, acc); acc = fmaf(hv[1], p0.y, acc);
            acc = fmaf(hv[2], p1.x, acc); acc = fmaf(hv[3], p1.y, acc);
            acc = fmaf(hv[4], p2.x, acc); acc = fmaf(hv[5], p2.y, acc);
            acc = fmaf(hv[6], p3.x, acc); acc = fmaf(hv[7], p3.y, acc);
            s[jj][g] = acc;
          }
      }
#pragma unroll
      for (int off = 32; off; off >>= 1)
#pragma unroll
        for (int jj = 0; jj < 2; ++jj)
#pragma unroll
          for (int g = 0; g < 3; ++g) s[jj][g] += __shfl_down(s[jj][g], off);
      if (lane == 0) {
#pragma unroll
        for (int jj = 0; jj < 2; ++jj) {
          int j = jbase + jj;
          float r = 1.f / (1.f + expf(-(pr[jj] + s[jj][0] + bh[jj][0])));
          float z = 1.f / (1.f + expf(-(pz[jj] + s[jj][1] + bh[jj][1])));
          float nn = tanhf(pn[jj] + r * (s[jj][2] + bh[jj][2]));
          float hn = (1.f - z) * nn + z * hsrc[j];
          pub(&sout[(size_t)t * N_NODES + j], hn);
          if (ysT) ysT[((size_t)j << 8) + t] = hn;
        }
        if (t + 1 < HIDDEN) {   // prefetch next gi under the barrier wait
          const size_t gn = (size_t)(t + 1) * (3 * N_NODES);
#pragma unroll
          for (int jj = 0; jj < 2; ++jj) {
            pr[jj] = gi[gn + jbase + jj];
            pz[jj] = gi[gn + 2048 + jbase + jj];
            pn[jj] = gi[gn + 4096 + jbase + jj];
          }
        }
      }
      grid_bar(gbar, gen0 + t + 1);
    }
  } else {
    // ---- f32: stage 2 j x 3 gates x 32 k into 48 float4 (192 VGPR) ----
    const float* wf = (const float*)whh + w_off;
    float4 W[2][3][8];
#pragma unroll
    for (int jj = 0; jj < 2; ++jj)
#pragma unroll
      for (int g = 0; g < 3; ++g) {
        const float* r = wf + (size_t)(jbase + jj + g * 2048) * 2048;
#pragma unroll
        for (int i = 0; i < 4; ++i) {
          const float4* q = (const float4*)(r + ((lane + (i << 6)) << 3));
          W[jj][g][2 * i] = q[0];
          W[jj][g][2 * i + 1] = q[1];
        }
      }
    for (int t = 0; t < HIDDEN; ++t) {
      const float* hsrc = t ? (sout + (size_t)(t - 1) * N_NODES) : hinit;
      float s[2][3] = {};
#pragma unroll
      for (int i = 0; i < 4; ++i) {
        const float4* hp = (const float4*)(hsrc + ((lane + (i << 6)) << 3));
        float4 va = hp[0], vb = hp[1];
#pragma unroll
        for (int jj = 0; jj < 2; ++jj)
#pragma unroll
          for (int g = 0; g < 3; ++g) {
            float4 xa = W[jj][g][2 * i], xb = W[jj][g][2 * i + 1];
            float acc = s[jj][g];
            acc = fmaf(va.x, xa.x, acc); acc = fmaf(va.y, xa.y, acc);
            acc = fmaf(va.z, xa.z, acc); acc = fmaf(va.w, xa.w, acc);
            acc = fmaf(vb.x, xb.x, acc); acc = fmaf(vb.y, xb.y, acc);
            acc = fmaf(vb.z, xb.z, acc); acc = fmaf(vb.w, xb.w, acc);
            s[jj][g] = acc;
          }
      }
#pragma unroll
      for (int off = 32; off; off >>= 1)
#pragma unroll
        for (int jj = 0; jj < 2; ++jj)
#pragma unroll
          for (int g = 0; g < 3; ++g) s[jj][g] += __shfl_down(s[jj][g], off);
      if (lane == 0) {
#pragma unroll
        for (int jj = 0; jj < 2; ++jj) {
          int j = jbase + jj;
          float r = 1.f / (1.f + expf(-(pr[jj] + s[jj][0] + bh[jj][0])));
          float z = 1.f / (1.f + expf(-(pz[jj] + s[jj][1] + bh[jj][1])));
          float nn = tanhf(pn[jj] + r * (s[jj][2] + bh[jj][2]));
          float hn = (1.f - z) * nn + z * hsrc[j];
          pub(&sout[(size_t)t * N_NODES + j], hn);
          if (ysT) ysT[((size_t)j << 8) + t] = hn;
        }
        if (t + 1 < HIDDEN) {
          const size_t gn = (size_t)(t + 1) * (3 * N_NODES);
#pragma unroll
          for (int jj = 0; jj < 2; ++jj) {
            pr[jj] = gi[gn + jbase + jj];
            pz[jj] = gi[gn + 2048 + jbase + jj];
            pn[jj] = gi[gn + 4096 + jbase + jj];
          }
        }
      }
      grid_bar(gbar, gen0 + t + 1);
    }
  }
}

// ---------- one GRU time step (fallback path if cooperative launch is refused) ----------
__global__ __launch_bounds__(256) void k_gru_step(const float* __restrict__ gi,
                                                  const void* __restrict__ whh,
                                                  const void* __restrict__ bhh,
                                                  const int* __restrict__ flags,
                                                  const float* __restrict__ hprev,
                                                  float* __restrict__ ysrow,
                                                  float* __restrict__ ysT,
                                                  int t, size_t w_off, size_t b_off) {
  const int F32 = flags[0];
  int j = blockIdx.x, tid = threadIdx.x;
  int k0 = tid << 3;
  const float4* hp4 = (const float4*)(hprev + k0);
  float4 hA = hp4[0], hB = hp4[1];
  F8 w0 = load8(whh, w_off + ((size_t)j << 11) + k0, F32);
  F8 w1 = load8(whh, w_off + ((size_t)(j + 2048) << 11) + k0, F32);
  F8 w2 = load8(whh, w_off + ((size_t)(j + 4096) << 11) + k0, F32);
  float hv[8] = {hA.x, hA.y, hA.z, hA.w, hB.x, hB.y, hB.z, hB.w};
  float s0 = 0.f, s1 = 0.f, s2 = 0.f;
#pragma unroll
  for (int u = 0; u < 8; ++u) {
    s0 = fmaf(hv[u], w0.v[u], s0);
    s1 = fmaf(hv[u], w1.v[u], s1);
    s2 = fmaf(hv[u], w2.v[u], s2);
  }
#pragma unroll
  for (int off = 32; off; off >>= 1) {
    s0 += __shfl_down(s0, off);
    s1 += __shfl_down(s1, off);
    s2 += __shfl_down(s2, off);
  }
  __shared__ float red[12];
  int wid = tid >> 6, lane = tid & 63;
  if (lane == 0) { red[wid] = s0; red[4 + wid] = s1; red[8 + wid] = s2; }
  __syncthreads();
  if (tid == 0) {
    float d0 = red[0] + red[1] + red[2] + red[3];
    float d1 = red[4] + red[5] + red[6] + red[7];
    float d2 = red[8] + red[9] + red[10] + red[11];
    const size_t g = (size_t)t * (3 * N_NODES);
    float gir = gi[g + j], giz = gi[g + 2048 + j], gin = gi[g + 4096 + j];
    float ghr = d0 + ldf(bhh, b_off + j, F32);
    float ghz = d1 + ldf(bhh, b_off + 2048 + j, F32);
    float ghn = d2 + ldf(bhh, b_off + 4096 + j, F32);
    float r = 1.f / (1.f + expf(-(gir + ghr)));
    float z = 1.f / (1.f + expf(-(giz + ghz)));
    float nn = tanhf(gin + r * ghn);
    float hn = (1.f - z) * nn + z * hprev[j];
    ysrow[j] = hn;
    if (ysT) ysT[(size_t)j * HIDDEN + t] = hn;
  }
}

// ---------- final linear ----------
__global__ __launch_bounds__(256) void k_final(const float* __restrict__ ysT,
                                               const void* __restrict__ lw,
                                               const void* __restrict__ lb,
                                               const int* __restrict__ flags,
                                               void* __restrict__ outp) {
  const int F32 = flags[0];
  __shared__ float row[HIDDEN];
  int n = blockIdx.x, tid = threadIdx.x;
  row[tid] = ysT[(size_t)n * HIDDEN + tid];
  __syncthreads();
  if (tid < STEP_AHEAD) {
    float acc = ldf(lb, tid, F32);
    for (int t = 0; t < HIDDEN; ++t)
      acc = fmaf(row[t], ldf(lw, (size_t)t * STEP_AHEAD + tid, F32), acc);
    if (F32) ((float*)outp)[(size_t)n * STEP_AHEAD + tid] = acc;
    else ((__hip_bfloat16*)outp)[(size_t)n * STEP_AHEAD + tid] = __float2bfloat16(acc);
  }
}

extern "C" void kernel_launch(void* const* d_in, const int* in_sizes, int n_in,
                              void* d_out, int out_size, void* d_ws, size_t ws_size,
                              hipStream_t stream) {
  const void* x   = d_in[0];
  const void* ei  = d_in[1];
  const void* ew  = d_in[2];
  const void* cw  = d_in[3];
  const void* cb  = d_in[4];
  const void* gw  = d_in[5];
  const void* gb  = d_in[6];
  const void* wih = d_in[7];
  const void* whh = d_in[8];
  const void* bih = d_in[9];
  const void* bhh = d_in[10];
  const void* lw  = d_in[11];
  const void* lb  = d_in[12];

  // workspace layout (floats), lifetime-aliased (~13.2 MB)
  float* ws = (float*)d_ws;
  float* gi   = ws;                                // 1,572,864 f (6 MB)
  float* out0 = ws;                                // aliases gi[0:1M) - dead before gi written
  float* seqA = ws + 1572864;                      // 524,288 f
  float* seqB = seqA + 524288;                     // 524,288 f
  float* h0   = seqB + 524288;                     // 524,288 f (dead after k_agg)
  float* ysT  = h0;                                // aliases h0 - written only in layer 2
  float* zreg = h0 + 524288;                       // 8,192 f zeroed: deg,cnt,cur,hinit
  float* deg   = zreg;
  int*   cnt   = (int*)(zreg + N_NODES);
  int*   cur   = (int*)(zreg + 2 * N_NODES);
  float* hinit = zreg + 3 * N_NODES;
  float* dinv = zreg + 4 * N_NODES;                // 2,048 f
  int*   csr_src = (int*)(dinv + N_NODES);         // 65,536
  float* csr_nrm = (float*)(csr_src + N_EDGES);    // 65,536
  int*   offs = (int*)(csr_nrm + N_EDGES);         // 2,048
  int*   flags = offs + N_NODES;                   // 2
  int*   gbar = cur;                               // reuse cursor region (dead after k_scatter)

  k_detect<<<1, 64, 0, stream>>>(x, ei, flags);
  (void)hipMemsetAsync(zreg, 0, 4 * N_NODES * sizeof(float), stream);

  k_conv<<<(N_NODES * SEQ) / 256, 256, 0, stream>>>(x, cw, cb, flags, out0);
  k_gemm_h0<<<N_NODES, 256, 0, stream>>>(out0, gw, flags, h0);
  k_deg<<<N_EDGES / 256, 256, 0, stream>>>(ei, ew, flags, deg, cnt);
  k_dinv<<<N_NODES / 256, 256, 0, stream>>>(deg, dinv);
  k_scan<<<1, 256, 0, stream>>>(cnt, offs);
  k_scatter<<<N_EDGES / 256, 256, 0, stream>>>(ei, ew, flags, dinv, offs, cur, csr_src, csr_nrm);
  k_agg<<<N_NODES, 256, 0, stream>>>(h0, csr_src, csr_nrm, offs, cnt, dinv, gb, flags, seqA);

  // zero barrier counters (cursor region is dead after k_scatter)
  (void)hipMemsetAsync(gbar, 0, 16 * sizeof(int), stream);

  const size_t WL = (size_t)3 * N_NODES * N_NODES;  // per-layer weight stride (elements)
  const size_t BL = (size_t)3 * N_NODES;            // per-layer bias stride (elements)
  for (int l = 0; l < N_LAYERS; ++l) {
    float* sin  = (l & 1) ? seqB : seqA;
    float* sout = (l & 1) ? seqA : seqB;
    k_gemm_nt<<<dim3(HIDDEN / BM, (3 * N_NODES) / BN), 256, 0, stream>>>(
        sin, wih, bih, flags, gi, HIDDEN, 3 * N_NODES, N_NODES,
        (size_t)l * WL, (size_t)l * BL);
    float* ysTp = (l == N_LAYERS - 1) ? ysT : (float*)nullptr;

    // cooperative launch: validates co-residency at launch; falls back if refused
    const float* a_gi = gi;   const void* a_whh = whh; const void* a_bhh = bhh;
    const int* a_flags = flags; const float* a_hinit = hinit;
    float* a_sout = sout;     float* a_ysT = ysTp;     int* a_gbar = gbar;
    size_t a_wo = (size_t)l * WL, a_bo = (size_t)l * BL;
    int a_g0 = l * HIDDEN;
    void* args[] = {&a_gi, &a_whh, &a_bhh, &a_flags, &a_hinit,
                    &a_sout, &a_ysT, &a_gbar, &a_wo, &a_bo, &a_g0};
    hipError_t rc = hipLaunchCooperativeKernel(
        reinterpret_cast<void*>(k_gru_persist),
        dim3(GRU_BLOCKS), dim3(256), args, 0, stream);
    if (rc != hipSuccess) {
      for (int t = 0; t < HIDDEN; ++t) {
        const float* hp = (t == 0) ? hinit : (sout + (size_t)(t - 1) * N_NODES);
        k_gru_step<<<N_NODES, 256, 0, stream>>>(
            gi, whh, bhh, flags, hp,
            sout + (size_t)t * N_NODES, ysTp, t, (size_t)l * WL, (size_t)l * BL);
      }
    }
  }
  k_final<<<N_NODES, 256, 0, stream>>>(ysT, lw, lb, flags, d_out);
}

// Round 5
// 7355.934 us; speedup vs baseline: 3.0766x; 1.5546x over previous
//
#include <hip/hip_runtime.h>
#include <hip/hip_bf16.h>
#include <cstdint>
#include <cstddef>

#define N_NODES 2048
#define SEQ 512
#define HIDDEN 256
#define N_FEAT 9
#define N_EDGES 65536
#define N_LAYERS 3
#define STEP_AHEAD 14

#define GRU_BLOCKS 256   // 256 blocks * 4 waves * 2 j/wave = 2048 j's; 1 block/CU
#define GB_STRIDE 64     // ints; 256B per barrier counter -> each on its own line

// ---------- helpers ----------
__device__ __forceinline__ float bf2f(__hip_bfloat16 b) { return __bfloat162float(b); }
__device__ __forceinline__ float2 bfpair(unsigned v) {
  float2 f;
  f.x = __uint_as_float(v << 16);
  f.y = __uint_as_float(v & 0xffff0000u);
  return f;
}
// dtype-adaptive scalar float load: f32flag ? float : bf16
__device__ __forceinline__ float ldf(const void* p, size_t i, int f32flag) {
  return f32flag ? ((const float*)p)[i] : bf2f(((const __hip_bfloat16*)p)[i]);
}
// dtype-adaptive index load: i64flag ? int64 : int32
__device__ __forceinline__ int ldi(const void* p, size_t i, int i64flag) {
  return i64flag ? (int)((const long long*)p)[i] : ((const int*)p)[i];
}
struct F8 { float v[8]; };
// load 8 consecutive float-typed elements (16B bf16 or 32B f32), element index i
__device__ __forceinline__ F8 load8(const void* p, size_t i, int f32flag) {
  F8 r;
  if (f32flag) {
    const float4* q = (const float4*)((const float*)p + i);
    float4 a = q[0], b = q[1];
    r.v[0]=a.x; r.v[1]=a.y; r.v[2]=a.z; r.v[3]=a.w;
    r.v[4]=b.x; r.v[5]=b.y; r.v[6]=b.z; r.v[7]=b.w;
  } else {
    uint4 u = *(const uint4*)((const __hip_bfloat16*)p + i);
    float2 a = bfpair(u.x), b = bfpair(u.y), c = bfpair(u.z), d = bfpair(u.w);
    r.v[0]=a.x; r.v[1]=a.y; r.v[2]=b.x; r.v[3]=b.y;
    r.v[4]=c.x; r.v[5]=c.y; r.v[6]=d.x; r.v[7]=d.y;
  }
  return r;
}

// ---------- dtype detector: flags[0]=1 if floats are f32; flags[1]=1 if edge_index is int64 ----------
__global__ void k_detect(const void* __restrict__ x, const void* __restrict__ ei,
                         int* __restrict__ flags) {
  if (blockIdx.x == 0 && threadIdx.x == 0) {
    const unsigned short* hb = (const unsigned short*)x;
    int abn = 0;
    for (int i = 0; i < 4096; ++i) {
      unsigned short h = hb[i * 64];
      unsigned e = (h >> 7) & 0xFF;
      if (e > 140 || (e != 0 && e < 114)) abn++;
    }
    flags[0] = (abn > 256) ? 1 : 0;
    const int* ip = (const int*)ei;
    int nz = 0;
    for (int i = 0; i < 1024; ++i) nz += (ip[2 * i + 1] != 0);
    flags[1] = (nz == 0) ? 1 : 0;
  }
}

// ---------- 1x1 conv over channels ----------
__global__ __launch_bounds__(256) void k_conv(const void* __restrict__ x,
                                              const void* __restrict__ cw,
                                              const void* __restrict__ cb,
                                              const int* __restrict__ flags,
                                              float* __restrict__ out0) {
  const int F32 = flags[0];
  int i = blockIdx.x * 256 + threadIdx.x;
  float acc = ldf(cb, 0, F32);
#pragma unroll
  for (int f = 0; f < N_FEAT; ++f)
    acc += ldf(x, (size_t)f * (N_NODES * SEQ) + i, F32) * ldf(cw, f, F32);
  out0[i] = acc;
}

// ---------- h0 = out0(2048x512) @ gcn_w(512x256) ----------
__global__ __launch_bounds__(256) void k_gemm_h0(const float* __restrict__ out0,
                                                 const void* __restrict__ gw,
                                                 const int* __restrict__ flags,
                                                 float* __restrict__ h0) {
  const int F32 = flags[0];
  __shared__ float row[SEQ];
  int n = blockIdx.x, tid = threadIdx.x;
  row[tid] = out0[(size_t)n * SEQ + tid];
  row[tid + 256] = out0[(size_t)n * SEQ + 256 + tid];
  __syncthreads();
  float acc = 0.f;
#pragma unroll 4
  for (int s = 0; s < SEQ; ++s)
    acc = fmaf(row[s], ldf(gw, (size_t)s * HIDDEN + tid, F32), acc);
  h0[(size_t)n * HIDDEN + tid] = acc;
}

// ---------- degree + in-degree count ----------
__global__ __launch_bounds__(256) void k_deg(const void* __restrict__ ei,
                                             const void* __restrict__ ew,
                                             const int* __restrict__ flags,
                                             float* __restrict__ deg, int* __restrict__ cnt) {
  const int F32 = flags[0], I64 = flags[1];
  int e = blockIdx.x * 256 + threadIdx.x;
  if (e < N_EDGES) {
    int c = ldi(ei, (size_t)N_EDGES + e, I64);
    atomicAdd(&deg[c], ldf(ew, e, F32));
    atomicAdd(&cnt[c], 1);
  }
}

// ---------- dinv = rsqrt(deg + 1) ----------
__global__ __launch_bounds__(256) void k_dinv(const float* __restrict__ deg,
                                              float* __restrict__ dinv) {
  int n = blockIdx.x * 256 + threadIdx.x;
  dinv[n] = rsqrtf(deg[n] + 1.0f);
}

// ---------- exclusive scan of cnt[2048] -> offs ----------
__global__ __launch_bounds__(256) void k_scan(const int* __restrict__ cnt, int* __restrict__ offs) {
  __shared__ int s[N_NODES];
  __shared__ int csum[64];
  int tid = threadIdx.x;
  for (int k = tid; k < N_NODES; k += 256) s[k] = cnt[k];
  __syncthreads();
  if (tid < 64) {
    int a = 0;
    for (int k = 0; k < 32; ++k) a += s[tid * 32 + k];
    csum[tid] = a;
  }
  __syncthreads();
  if (tid == 0) {
    int run = 0;
    for (int i = 0; i < 64; ++i) { int v = csum[i]; csum[i] = run; run += v; }
  }
  __syncthreads();
  if (tid < 64) {
    int run = csum[tid];
    for (int k = 0; k < 32; ++k) {
      int n = tid * 32 + k;
      offs[n] = run;
      run += s[n];
    }
  }
}

// ---------- scatter edges into CSR grouped by target ----------
__global__ __launch_bounds__(256) void k_scatter(const void* __restrict__ ei,
                                                 const void* __restrict__ ew,
                                                 const int* __restrict__ flags,
                                                 const float* __restrict__ dinv,
                                                 const int* __restrict__ offs,
                                                 int* __restrict__ cursor,
                                                 int* __restrict__ csr_src,
                                                 float* __restrict__ csr_nrm) {
  const int F32 = flags[0], I64 = flags[1];
  int e = blockIdx.x * 256 + threadIdx.x;
  if (e < N_EDGES) {
    int r = ldi(ei, e, I64), c = ldi(ei, (size_t)N_EDGES + e, I64);
    float w = ldf(ew, e, F32);
    int pos = offs[c] + atomicAdd(&cursor[c], 1);
    csr_src[pos] = r;
    csr_nrm[pos] = dinv[r] * w * dinv[c];
  }
}

// ---------- aggregate + bias + relu, write transposed seq0[c*N + n] ----------
__global__ __launch_bounds__(256) void k_agg(const float* __restrict__ h0,
                                             const int* __restrict__ csr_src,
                                             const float* __restrict__ csr_nrm,
                                             const int* __restrict__ offs,
                                             const int* __restrict__ cnt,
                                             const float* __restrict__ dinv,
                                             const void* __restrict__ gb,
                                             const int* __restrict__ flags,
                                             float* __restrict__ seq0) {
  const int F32 = flags[0];
  int n = blockIdx.x, c = threadIdx.x;
  float acc = dinv[n] * dinv[n] * h0[(size_t)n * HIDDEN + c];
  int st = offs[n], en = st + cnt[n];
  for (int p = st; p < en; ++p)
    acc = fmaf(csr_nrm[p], h0[(size_t)csr_src[p] * HIDDEN + c], acc);
  float h = acc + ldf(gb, c, F32);
  seq0[(size_t)c * N_NODES + n] = h > 0.f ? h : 0.f;
}

// ---------- C(MxN) = A(MxK,f32) @ B(NxK)^T + bias(N); B/bias offset by layer in elements ----------
#define BM 32
#define BN 64
#define BK 32
__global__ __launch_bounds__(256) void k_gemm_nt(const float* __restrict__ A,
                                                 const void* __restrict__ B,
                                                 const void* __restrict__ bias,
                                                 const int* __restrict__ flags,
                                                 float* __restrict__ C,
                                                 int M, int N, int K,
                                                 size_t b_off, size_t bias_off) {
  const int F32 = flags[0];
  __shared__ float As[BM][BK + 1];
  __shared__ float Bs[BN][BK + 1];
  int tid = threadIdx.x;
  int bm = blockIdx.x * BM, bn = blockIdx.y * BN;
  int tx = tid & 15, ty = tid >> 4;
  float acc[2][4] = {};
  for (int k0 = 0; k0 < K; k0 += BK) {
    {
      int row = tid >> 3, kc = (tid & 7) << 2;   // 32 rows x 8 float4
      float4 v = *(const float4*)(A + (size_t)(bm + row) * K + k0 + kc);
      As[row][kc] = v.x; As[row][kc + 1] = v.y; As[row][kc + 2] = v.z; As[row][kc + 3] = v.w;
    }
    {
      int row = tid >> 2, kc = (tid & 3) << 3;
      F8 b8 = load8(B, b_off + (size_t)(bn + row) * K + k0 + kc, F32);
#pragma unroll
      for (int u = 0; u < 8; ++u) Bs[row][kc + u] = b8.v[u];
    }
    __syncthreads();
#pragma unroll
    for (int kk = 0; kk < BK; ++kk) {
      float a[2], b[4];
#pragma unroll
      for (int i = 0; i < 2; ++i) a[i] = As[ty * 2 + i][kk];
#pragma unroll
      for (int j = 0; j < 4; ++j) b[j] = Bs[tx * 4 + j][kk];
#pragma unroll
      for (int i = 0; i < 2; ++i)
#pragma unroll
        for (int j = 0; j < 4; ++j) acc[i][j] = fmaf(a[i], b[j], acc[i][j]);
    }
    __syncthreads();
  }
#pragma unroll
  for (int i = 0; i < 2; ++i)
#pragma unroll
    for (int j = 0; j < 4; ++j) {
      int m = bm + ty * 2 + i, n = bn + tx * 4 + j;
      C[(size_t)m * N + n] = acc[i][j] + ldf(bias, bias_off + n, F32);
    }
}

// ---------- grid barrier v3: tree arrive, PADDED counters (one per 256B line) ----------
// c[grp*64] for grp=0..7 (32 blocks each), c[8*64] root, c[9*64] generation.
// Gen word lives on its own line -> poll reads never serialize behind arrival RMWs.
// Counters are CUMULATIVE (monotone) -> no reset, replay-safe.
// h published via agent-scope atomic stores (write-through), drained by the vmcnt(0)
// of __syncthreads before arrival -> no release fence. Freshness: one ACQUIRE load
// after the poll (L1/L2 invalidate); 1 block/CU so thread-0's inv covers the CU.
__device__ __forceinline__ void grid_bar(int* c, int g) {
  __syncthreads();
  if (threadIdx.x == 0) {
    int grp = blockIdx.x >> 5;
    int old = __hip_atomic_fetch_add(&c[grp * GB_STRIDE], 1, __ATOMIC_RELAXED, __HIP_MEMORY_SCOPE_AGENT);
    if (old == 32 * g - 1) {
      int r = __hip_atomic_fetch_add(&c[8 * GB_STRIDE], 1, __ATOMIC_RELAXED, __HIP_MEMORY_SCOPE_AGENT);
      if (r == 8 * g - 1)
        __hip_atomic_store(&c[9 * GB_STRIDE], g, __ATOMIC_RELAXED, __HIP_MEMORY_SCOPE_AGENT);
    }
    int spins = 0;
    while (__hip_atomic_load(&c[9 * GB_STRIDE], __ATOMIC_RELAXED, __HIP_MEMORY_SCOPE_AGENT) < g) {
      __builtin_amdgcn_s_sleep(2);
      if (++spins > (1 << 16)) break;  // bounded: fails visibly, never hangs
    }
    (void)__hip_atomic_load(&c[9 * GB_STRIDE], __ATOMIC_ACQUIRE, __HIP_MEMORY_SCOPE_AGENT);
  }
  __syncthreads();
}

// publish one h value to the coherence point (write-through, vmcnt-tracked)
__device__ __forceinline__ void pub(float* p, float v) {
  __hip_atomic_store(p, v, __ATOMIC_RELAXED, __HIP_MEMORY_SCOPE_AGENT);
}

// ---------- persistent GRU layer (cooperative launch): all 256 steps in one kernel ----------
// 256 blocks x 256 threads, 1 block/CU. Each wave owns 2 hidden indices; its whh slice
// is register-staged once per layer (bf16: 96 VGPR, f32: 192 VGPR).
__global__ __launch_bounds__(256, 1) void k_gru_persist(
    const float* __restrict__ gi, const void* __restrict__ whh,
    const void* __restrict__ bhh, const int* __restrict__ flags,
    const float* __restrict__ hinit, float* __restrict__ sout,
    float* __restrict__ ysT, int* __restrict__ gbar,
    size_t w_off, size_t b_off, int gen0) {
  const int F32 = flags[0];
  const int tid = threadIdx.x;
  const int wv = tid >> 6, lane = tid & 63;
  const int jbase = (blockIdx.x << 3) + (wv << 1);   // this wave's 2 j's

  float bh[2][3];
#pragma unroll
  for (int jj = 0; jj < 2; ++jj)
#pragma unroll
    for (int g = 0; g < 3; ++g) bh[jj][g] = 0.f;
  float pr[2], pz[2], pn[2];   // prefetched gi gates for current t
  if (lane == 0) {
#pragma unroll
    for (int jj = 0; jj < 2; ++jj) {
#pragma unroll
      for (int g = 0; g < 3; ++g)
        bh[jj][g] = ldf(bhh, b_off + (size_t)g * 2048 + jbase + jj, F32);
      pr[jj] = gi[jbase + jj];
      pz[jj] = gi[2048 + jbase + jj];
      pn[jj] = gi[4096 + jbase + jj];
    }
  }

  if (!F32) {
    // ---- bf16: stage 2 j x 3 gates x 32 k into 24 uint4 (96 VGPR) ----
    const __hip_bfloat16* wb = (const __hip_bfloat16*)whh + w_off;
    uint4 W[2][3][4];
#pragma unroll
    for (int jj = 0; jj < 2; ++jj)
#pragma unroll
      for (int g = 0; g < 3; ++g) {
        const __hip_bfloat16* r = wb + (size_t)(jbase + jj + g * 2048) * 2048;
#pragma unroll
        for (int i = 0; i < 4; ++i)
          W[jj][g][i] = *(const uint4*)(r + ((lane + (i << 6)) << 3));
      }
    for (int t = 0; t < HIDDEN; ++t) {
      const float* hsrc = t ? (sout + (size_t)(t - 1) * N_NODES) : hinit;
      float s[2][3] = {};
#pragma unroll
      for (int i = 0; i < 4; ++i) {
        const float4* hp = (const float4*)(hsrc + ((lane + (i << 6)) << 3));
        float4 va = hp[0], vb = hp[1];
        float hv[8] = {va.x, va.y, va.z, va.w, vb.x, vb.y, vb.z, vb.w};
#pragma unroll
        for (int jj = 0; jj < 2; ++jj)
#pragma unroll
          for (int g = 0; g < 3; ++g) {
            uint4 w = W[jj][g][i];
            float2 p0 = bfpair(w.x), p1 = bfpair(w.y), p2 = bfpair(w.z), p3 = bfpair(w.w);
            float acc = s[jj][g];
            acc = fmaf(hv[0], p0.x, acc); acc = fmaf(hv[1], p0.y, acc);
            acc = fmaf(hv[2], p1.x, acc); acc = fmaf(hv[3], p1.y, acc);
            acc = fmaf(hv[4], p2.x, acc); acc = fmaf(hv[5], p2.y, acc);
            acc = fmaf(hv[6], p3.x, acc); acc = fmaf(hv[7], p3.y, acc);
            s[jj][g] = acc;
          }
      }
#pragma unroll
      for (int off = 32; off; off >>= 1)
#pragma unroll
        for (int jj = 0; jj < 2; ++jj)
#pragma unroll
          for (int g = 0; g < 3; ++g) s[jj][g] += __shfl_down(s[jj][g], off);
      if (lane == 0) {
#pragma unroll
        for (int jj = 0; jj < 2; ++jj) {
          int j = jbase + jj;
          float r = 1.f / (1.f + expf(-(pr[jj] + s[jj][0] + bh[jj][0])));
          float z = 1.f / (1.f + expf(-(pz[jj] + s[jj][1] + bh[jj][1])));
          float nn = tanhf(pn[jj] + r * (s[jj][2] + bh[jj][2]));
          float hn = (1.f - z) * nn + z * hsrc[j];
          pub(&sout[(size_t)t * N_NODES + j], hn);
          if (ysT) ysT[((size_t)j << 8) + t] = hn;
        }
        if (t + 1 < HIDDEN) {   // prefetch next gi under the barrier wait
          const size_t gn = (size_t)(t + 1) * (3 * N_NODES);
#pragma unroll
          for (int jj = 0; jj < 2; ++jj) {
            pr[jj] = gi[gn + jbase + jj];
            pz[jj] = gi[gn + 2048 + jbase + jj];
            pn[jj] = gi[gn + 4096 + jbase + jj];
          }
        }
      }
      grid_bar(gbar, gen0 + t + 1);
    }
  } else {
    // ---- f32: stage 2 j x 3 gates x 32 k into 48 float4 (192 VGPR) ----
    const float* wf = (const float*)whh + w_off;
    float4 W[2][3][8];
#pragma unroll
    for (int jj = 0; jj < 2; ++jj)
#pragma unroll
      for (int g = 0; g < 3; ++g) {
        const float* r = wf + (size_t)(jbase + jj + g * 2048) * 2048;
#pragma unroll
        for (int i = 0; i < 4; ++i) {
          const float4* q = (const float4*)(r + ((lane + (i << 6)) << 3));
          W[jj][g][2 * i] = q[0];
          W[jj][g][2 * i + 1] = q[1];
        }
      }
    for (int t = 0; t < HIDDEN; ++t) {
      const float* hsrc = t ? (sout + (size_t)(t - 1) * N_NODES) : hinit;
      float s[2][3] = {};
#pragma unroll
      for (int i = 0; i < 4; ++i) {
        const float4* hp = (const float4*)(hsrc + ((lane + (i << 6)) << 3));
        float4 va = hp[0], vb = hp[1];
#pragma unroll
        for (int jj = 0; jj < 2; ++jj)
#pragma unroll
          for (int g = 0; g < 3; ++g) {
            float4 xa = W[jj][g][2 * i], xb = W[jj][g][2 * i + 1];
            float acc = s[jj][g];
            acc = fmaf(va.x, xa.x, acc); acc = fmaf(va.y, xa.y, acc);
            acc = fmaf(va.z, xa.z, acc); acc = fmaf(va.w, xa.w, acc);
            acc = fmaf(vb.x, xb.x, acc); acc = fmaf(vb.y, xb.y, acc);
            acc = fmaf(vb.z, xb.z, acc); acc = fmaf(vb.w, xb.w, acc);
            s[jj][g] = acc;
          }
      }
#pragma unroll
      for (int off = 32; off; off >>= 1)
#pragma unroll
        for (int jj = 0; jj < 2; ++jj)
#pragma unroll
          for (int g = 0; g < 3; ++g) s[jj][g] += __shfl_down(s[jj][g], off);
      if (lane == 0) {
#pragma unroll
        for (int jj = 0; jj < 2; ++jj) {
          int j = jbase + jj;
          float r = 1.f / (1.f + expf(-(pr[jj] + s[jj][0] + bh[jj][0])));
          float z = 1.f / (1.f + expf(-(pz[jj] + s[jj][1] + bh[jj][1])));
          float nn = tanhf(pn[jj] + r * (s[jj][2] + bh[jj][2]));
          float hn = (1.f - z) * nn + z * hsrc[j];
          pub(&sout[(size_t)t * N_NODES + j], hn);
          if (ysT) ysT[((size_t)j << 8) + t] = hn;
        }
        if (t + 1 < HIDDEN) {
          const size_t gn = (size_t)(t + 1) * (3 * N_NODES);
#pragma unroll
          for (int jj = 0; jj < 2; ++jj) {
            pr[jj] = gi[gn + jbase + jj];
            pz[jj] = gi[gn + 2048 + jbase + jj];
            pn[jj] = gi[gn + 4096 + jbase + jj];
          }
        }
      }
      grid_bar(gbar, gen0 + t + 1);
    }
  }
}

// ---------- one GRU time step (fallback path if cooperative launch is refused) ----------
__global__ __launch_bounds__(256) void k_gru_step(const float* __restrict__ gi,
                                                  const void* __restrict__ whh,
                                                  const void* __restrict__ bhh,
                                                  const int* __restrict__ flags,
                                                  const float* __restrict__ hprev,
                                                  float* __restrict__ ysrow,
                                                  float* __restrict__ ysT,
                                                  int t, size_t w_off, size_t b_off) {
  const int F32 = flags[0];
  int j = blockIdx.x, tid = threadIdx.x;
  int k0 = tid << 3;
  const float4* hp4 = (const float4*)(hprev + k0);
  float4 hA = hp4[0], hB = hp4[1];
  F8 w0 = load8(whh, w_off + ((size_t)j << 11) + k0, F32);
  F8 w1 = load8(whh, w_off + ((size_t)(j + 2048) << 11) + k0, F32);
  F8 w2 = load8(whh, w_off + ((size_t)(j + 4096) << 11) + k0, F32);
  float hv[8] = {hA.x, hA.y, hA.z, hA.w, hB.x, hB.y, hB.z, hB.w};
  float s0 = 0.f, s1 = 0.f, s2 = 0.f;
#pragma unroll
  for (int u = 0; u < 8; ++u) {
    s0 = fmaf(hv[u], w0.v[u], s0);
    s1 = fmaf(hv[u], w1.v[u], s1);
    s2 = fmaf(hv[u], w2.v[u], s2);
  }
#pragma unroll
  for (int off = 32; off; off >>= 1) {
    s0 += __shfl_down(s0, off);
    s1 += __shfl_down(s1, off);
    s2 += __shfl_down(s2, off);
  }
  __shared__ float red[12];
  int wid = tid >> 6, lane = tid & 63;
  if (lane == 0) { red[wid] = s0; red[4 + wid] = s1; red[8 + wid] = s2; }
  __syncthreads();
  if (tid == 0) {
    float d0 = red[0] + red[1] + red[2] + red[3];
    float d1 = red[4] + red[5] + red[6] + red[7];
    float d2 = red[8] + red[9] + red[10] + red[11];
    const size_t g = (size_t)t * (3 * N_NODES);
    float gir = gi[g + j], giz = gi[g + 2048 + j], gin = gi[g + 4096 + j];
    float ghr = d0 + ldf(bhh, b_off + j, F32);
    float ghz = d1 + ldf(bhh, b_off + 2048 + j, F32);
    float ghn = d2 + ldf(bhh, b_off + 4096 + j, F32);
    float r = 1.f / (1.f + expf(-(gir + ghr)));
    float z = 1.f / (1.f + expf(-(giz + ghz)));
    float nn = tanhf(gin + r * ghn);
    float hn = (1.f - z) * nn + z * hprev[j];
    ysrow[j] = hn;
    if (ysT) ysT[(size_t)j * HIDDEN + t] = hn;
  }
}

// ---------- final linear ----------
__global__ __launch_bounds__(256) void k_final(const float* __restrict__ ysT,
                                               const void* __restrict__ lw,
                                               const void* __restrict__ lb,
                                               const int* __restrict__ flags,
                                               void* __restrict__ outp) {
  const int F32 = flags[0];
  __shared__ float row[HIDDEN];
  int n = blockIdx.x, tid = threadIdx.x;
  row[tid] = ysT[(size_t)n * HIDDEN + tid];
  __syncthreads();
  if (tid < STEP_AHEAD) {
    float acc = ldf(lb, tid, F32);
    for (int t = 0; t < HIDDEN; ++t)
      acc = fmaf(row[t], ldf(lw, (size_t)t * STEP_AHEAD + tid, F32), acc);
    if (F32) ((float*)outp)[(size_t)n * STEP_AHEAD + tid] = acc;
    else ((__hip_bfloat16*)outp)[(size_t)n * STEP_AHEAD + tid] = __float2bfloat16(acc);
  }
}

extern "C" void kernel_launch(void* const* d_in, const int* in_sizes, int n_in,
                              void* d_out, int out_size, void* d_ws, size_t ws_size,
                              hipStream_t stream) {
  const void* x   = d_in[0];
  const void* ei  = d_in[1];
  const void* ew  = d_in[2];
  const void* cw  = d_in[3];
  const void* cb  = d_in[4];
  const void* gw  = d_in[5];
  const void* gb  = d_in[6];
  const void* wih = d_in[7];
  const void* whh = d_in[8];
  const void* bih = d_in[9];
  const void* bhh = d_in[10];
  const void* lw  = d_in[11];
  const void* lb  = d_in[12];

  // workspace layout (floats), lifetime-aliased (~13.2 MB)
  float* ws = (float*)d_ws;
  float* gi   = ws;                                // 1,572,864 f (6 MB)
  float* out0 = ws;                                // aliases gi[0:1M) - dead before gi written
  float* seqA = ws + 1572864;                      // 524,288 f
  float* seqB = seqA + 524288;                     // 524,288 f
  float* h0   = seqB + 524288;                     // 524,288 f (dead after k_agg)
  float* ysT  = h0;                                // aliases h0 - written only in layer 2
  float* zreg = h0 + 524288;                       // 8,192 f zeroed: deg,cnt,cur,hinit
  float* deg   = zreg;
  int*   cnt   = (int*)(zreg + N_NODES);
  int*   cur   = (int*)(zreg + 2 * N_NODES);
  float* hinit = zreg + 3 * N_NODES;
  float* dinv = zreg + 4 * N_NODES;                // 2,048 f
  int*   csr_src = (int*)(dinv + N_NODES);         // 65,536
  float* csr_nrm = (float*)(csr_src + N_EDGES);    // 65,536
  int*   offs = (int*)(csr_nrm + N_EDGES);         // 2,048
  int*   flags = offs + N_NODES;                   // 2
  int*   gbar = cur;                               // reuse cursor region (dead after k_scatter; 8KB > 10*256B)

  k_detect<<<1, 64, 0, stream>>>(x, ei, flags);
  (void)hipMemsetAsync(zreg, 0, 4 * N_NODES * sizeof(float), stream);

  k_conv<<<(N_NODES * SEQ) / 256, 256, 0, stream>>>(x, cw, cb, flags, out0);
  k_gemm_h0<<<N_NODES, 256, 0, stream>>>(out0, gw, flags, h0);
  k_deg<<<N_EDGES / 256, 256, 0, stream>>>(ei, ew, flags, deg, cnt);
  k_dinv<<<N_NODES / 256, 256, 0, stream>>>(deg, dinv);
  k_scan<<<1, 256, 0, stream>>>(cnt, offs);
  k_scatter<<<N_EDGES / 256, 256, 0, stream>>>(ei, ew, flags, dinv, offs, cur, csr_src, csr_nrm);
  k_agg<<<N_NODES, 256, 0, stream>>>(h0, csr_src, csr_nrm, offs, cnt, dinv, gb, flags, seqA);

  // zero padded barrier counters (cursor region is dead after k_scatter)
  (void)hipMemsetAsync(gbar, 0, 10 * GB_STRIDE * sizeof(int), stream);

  const size_t WL = (size_t)3 * N_NODES * N_NODES;  // per-layer weight stride (elements)
  const size_t BL = (size_t)3 * N_NODES;            // per-layer bias stride (elements)
  for (int l = 0; l < N_LAYERS; ++l) {
    float* sin  = (l & 1) ? seqB : seqA;
    float* sout = (l & 1) ? seqA : seqB;
    k_gemm_nt<<<dim3(HIDDEN / BM, (3 * N_NODES) / BN), 256, 0, stream>>>(
        sin, wih, bih, flags, gi, HIDDEN, 3 * N_NODES, N_NODES,
        (size_t)l * WL, (size_t)l * BL);
    float* ysTp = (l == N_LAYERS - 1) ? ysT : (float*)nullptr;

    // cooperative launch: validates co-residency at launch; falls back if refused
    const float* a_gi = gi;   const void* a_whh = whh; const void* a_bhh = bhh;
    const int* a_flags = flags; const float* a_hinit = hinit;
    float* a_sout = sout;     float* a_ysT = ysTp;     int* a_gbar = gbar;
    size_t a_wo = (size_t)l * WL, a_bo = (size_t)l * BL;
    int a_g0 = l * HIDDEN;
    void* args[] = {&a_gi, &a_whh, &a_bhh, &a_flags, &a_hinit,
                    &a_sout, &a_ysT, &a_gbar, &a_wo, &a_bo, &a_g0};
    hipError_t rc = hipLaunchCooperativeKernel(
        reinterpret_cast<void*>(k_gru_persist),
        dim3(GRU_BLOCKS), dim3(256), args, 0, stream);
    if (rc != hipSuccess) {
      for (int t = 0; t < HIDDEN; ++t) {
        const float* hp = (t == 0) ? hinit : (sout + (size_t)(t - 1) * N_NODES);
        k_gru_step<<<N_NODES, 256, 0, stream>>>(
            gi, whh, bhh, flags, hp,
            sout + (size_t)t * N_NODES, ysTp, t, (size_t)l * WL, (size_t)l * BL);
      }
    }
  }
  k_final<<<N_NODES, 256, 0, stream>>>(ysT, lw, lb, flags, d_out);
}